// Round 1
// baseline (1583.615 us; speedup 1.0000x reference)
//
#include <hip/hip_runtime.h>

#define DEV __global__ __launch_bounds__(256)

constexpr int NN = 50000;   // nodes
constexpr int NE = 600000;  // edges
constexpr int D  = 128;     // emb dim
constexpr int NG = 500;     // graphs
constexpr int NL = 3;       // layers
constexpr int SCAN_B = 512;
constexpr int NBLK = (NN + SCAN_B - 1) / SCAN_B;  // 98

// ---------------- encoders / elementwise ----------------

// h0[n][d] = sum_i atom_emb[i][x[n][i]][d]   (thread = (node, 4 dims))
DEV void k_atom(const int* __restrict__ x, const float* __restrict__ emb,
                float* __restrict__ h) {
  int t = blockIdx.x * 256 + threadIdx.x;
  int n = t >> 5, c = (t & 31) * 4;
  if (n >= NN) return;
  float4 acc = make_float4(0.f, 0.f, 0.f, 0.f);
  #pragma unroll
  for (int i = 0; i < 9; ++i) {
    int v = x[n * 9 + i];
    float4 e = *(const float4*)(emb + ((size_t)(i * 128 + v)) * D + c);
    acc.x += e.x; acc.y += e.y; acc.z += e.z; acc.w += e.w;
  }
  *(float4*)(h + (size_t)n * D + c) = acc;
}

DEV void k_vninit(const float* __restrict__ src, float* __restrict__ vn) {
  int t = blockIdx.x * 256 + threadIdx.x;
  int g = t >> 5, c = (t & 31) * 4;
  if (g >= NG) return;
  *(float4*)(vn + (size_t)g * D + c) = *(const float4*)(src + c);
}

// hv = h + vn[batch]
DEV void k_hv(const float* __restrict__ h, const float* __restrict__ vn,
              const int* __restrict__ batch, float* __restrict__ hv) {
  int t = blockIdx.x * 256 + threadIdx.x;
  int n = t >> 5, c = (t & 31) * 4;
  if (n >= NN) return;
  float4 a = *(const float4*)(h + (size_t)n * D + c);
  float4 b = *(const float4*)(vn + (size_t)batch[n] * D + c);
  a.x += b.x; a.y += b.y; a.z += b.z; a.w += b.w;
  *(float4*)(hv + (size_t)n * D + c) = a;
}

// out = z*scale[c]+shift[c] (+relu)   (z is M x 128)
DEV void k_affine(const float* __restrict__ z, const float* __restrict__ scale,
                  const float* __restrict__ shift, float* __restrict__ outp,
                  int M, int relu) {
  int t = blockIdx.x * 256 + threadIdx.x;
  int n = t >> 5, c = (t & 31) * 4;
  if (n >= M) return;
  float4 v = *(const float4*)(z + (size_t)n * 128 + c);
  float4 sc = *(const float4*)(scale + c);
  float4 sh = *(const float4*)(shift + c);
  v.x = fmaf(v.x, sc.x, sh.x);
  v.y = fmaf(v.y, sc.y, sh.y);
  v.z = fmaf(v.z, sc.z, sh.z);
  v.w = fmaf(v.w, sc.w, sh.w);
  if (relu) {
    v.x = fmaxf(v.x, 0.f); v.y = fmaxf(v.y, 0.f);
    v.z = fmaxf(v.z, 0.f); v.w = fmaxf(v.w, 0.f);
  }
  *(float4*)(outp + (size_t)n * 128 + c) = v;
}

// ---------------- CSR build ----------------

DEV void k_hist(const int* __restrict__ ei, int* __restrict__ cnt) {
  int e = blockIdx.x * 256 + threadIdx.x;
  if (e < NE) atomicAdd(&cnt[ei[NE + e]], 1);
}

__global__ __launch_bounds__(SCAN_B) void k_scan_a(const int* __restrict__ cnt,
                                                   int* __restrict__ rowptr,
                                                   int* __restrict__ bsum) {
  __shared__ int sh[SCAN_B];
  int i = blockIdx.x * SCAN_B + threadIdx.x;
  int v = (i < NN) ? cnt[i] : 0;
  sh[threadIdx.x] = v;
  __syncthreads();
  for (int off = 1; off < SCAN_B; off <<= 1) {
    int u = (threadIdx.x >= (unsigned)off) ? sh[threadIdx.x - off] : 0;
    __syncthreads();
    sh[threadIdx.x] += u;
    __syncthreads();
  }
  if (i < NN) rowptr[i + 1] = sh[threadIdx.x];
  if (threadIdx.x == SCAN_B - 1) bsum[blockIdx.x] = sh[SCAN_B - 1];
}

__global__ void k_scan_b(int* __restrict__ bsum, int nb) {
  if (threadIdx.x == 0 && blockIdx.x == 0) {
    int acc = 0;
    for (int i = 0; i < nb; ++i) { int v = bsum[i]; bsum[i] = acc; acc += v; }
  }
}

__global__ __launch_bounds__(SCAN_B) void k_scan_c(int* __restrict__ rowptr,
                                                   const int* __restrict__ bsum) {
  int i = blockIdx.x * SCAN_B + threadIdx.x;
  if (i < NN) rowptr[i + 1] += bsum[blockIdx.x];
  if (i == 0) rowptr[0] = 0;
}

DEV void k_fill(const int* __restrict__ ei, const int* __restrict__ eattr,
                int* __restrict__ cursor, unsigned* __restrict__ csr) {
  int e = blockIdx.x * 256 + threadIdx.x;
  if (e >= NE) return;
  int dn = ei[NE + e];
  int p = atomicAdd(&cursor[dn], 1);
  unsigned a0 = (unsigned)eattr[e * 3 + 0];
  unsigned a1 = (unsigned)eattr[e * 3 + 1];
  unsigned a2 = (unsigned)eattr[e * 3 + 2];
  csr[p] = (unsigned)ei[e] | (a0 << 17) | (a1 << 20) | (a2 << 23);
}

// ---------------- edge aggregation (wave per node, no atomics) ----------------

DEV void k_agg(const float* __restrict__ hv, const unsigned* __restrict__ csr,
               const int* __restrict__ rowptr, const float* __restrict__ bond,
               float* __restrict__ agg) {
  __shared__ float eb[3 * 8 * D];  // 12 KB bond tables for this layer
  for (int i = threadIdx.x; i < 3 * 8 * D; i += 256) eb[i] = bond[i];
  __syncthreads();
  int wid = (blockIdx.x * 256 + threadIdx.x) >> 6;  // node id
  int lane = threadIdx.x & 63;
  if (wid >= NN) return;
  int d0 = lane * 2;
  float ax = 0.f, ay = 0.f;
  int p1 = rowptr[wid + 1];
  for (int p = rowptr[wid]; p < p1; ++p) {
    unsigned pk = csr[p];
    int s = pk & 0x1FFFF;
    float2 hvv = *(const float2*)(hv + (size_t)s * D + d0);
    float2 e0 = *(const float2*)(eb + (((pk >> 17) & 7u)) * D + d0);
    float2 e1 = *(const float2*)(eb + (8 + ((pk >> 20) & 7u)) * D + d0);
    float2 e2 = *(const float2*)(eb + (16 + ((pk >> 23) & 7u)) * D + d0);
    float mx = hvv.x + e0.x + e1.x + e2.x;
    float my = hvv.y + e0.y + e1.y + e2.y;
    ax += fmaxf(mx, 0.f);
    ay += fmaxf(my, 0.f);
  }
  *(float2*)(agg + (size_t)wid * D + d0) = make_float2(ax, ay);
}

// ---------------- GEMM + BN-stats epilogue ----------------
// Y[M x ldy cols window] = A' @ W + bias, where
//   AMODE 0: A' = A0
//   AMODE 1: A' = (1+*epsp)*A0 + A1
//   AMODE 2: A' = relu(A0*ascale[k] + ashift[k])
// Accumulates per-column sum / sumsq (of Y incl. bias) into colsum/colsq.
template <int KT, int AMODE>
__global__ __launch_bounds__(256) void k_gemm(
    int M, const float* __restrict__ A0, const float* __restrict__ A1,
    const float* __restrict__ epsp, const float* __restrict__ ascale,
    const float* __restrict__ ashift, const float* __restrict__ W, int ldw,
    const float* __restrict__ bias, float* __restrict__ Y, int ldy,
    float* __restrict__ colsum, float* __restrict__ colsq) {
  __shared__ float At[32][132];
  __shared__ float Bt[32][132];
  const int tid = threadIdx.x;
  const int tx = tid & 15, ty = tid >> 4;
  const int row0 = blockIdx.x * 128, col0 = blockIdx.y * 128;
  float acc[8][8];
  #pragma unroll
  for (int i = 0; i < 8; ++i)
    #pragma unroll
    for (int j = 0; j < 8; ++j) acc[i][j] = 0.f;
  float ef = 0.f;
  if (AMODE == 1) ef = 1.f + *epsp;

  for (int k0 = 0; k0 < KT; k0 += 32) {
    {  // stage A (transposed): 128 rows x 32 k
      const int r_ = tid >> 3;
      const int kq = (tid & 7) * 4;
      #pragma unroll
      for (int i = 0; i < 4; ++i) {
        int r = r_ + 32 * i;
        int gr = row0 + r;
        float4 v = make_float4(0.f, 0.f, 0.f, 0.f);
        if (gr < M) {
          v = *(const float4*)(A0 + (size_t)gr * KT + k0 + kq);
          if (AMODE == 1) {
            float4 g = *(const float4*)(A1 + (size_t)gr * KT + k0 + kq);
            v.x = fmaf(ef, v.x, g.x); v.y = fmaf(ef, v.y, g.y);
            v.z = fmaf(ef, v.z, g.z); v.w = fmaf(ef, v.w, g.w);
          } else if (AMODE == 2) {
            int kk = k0 + kq;
            v.x = fmaxf(fmaf(v.x, ascale[kk + 0], ashift[kk + 0]), 0.f);
            v.y = fmaxf(fmaf(v.y, ascale[kk + 1], ashift[kk + 1]), 0.f);
            v.z = fmaxf(fmaf(v.z, ascale[kk + 2], ashift[kk + 2]), 0.f);
            v.w = fmaxf(fmaf(v.w, ascale[kk + 3], ashift[kk + 3]), 0.f);
          }
        }
        At[kq + 0][r] = v.x; At[kq + 1][r] = v.y;
        At[kq + 2][r] = v.z; At[kq + 3][r] = v.w;
      }
    }
    {  // stage B: 32 k x 128 cols (same layout as global)
      const int kk = tid >> 3;
      const int cq = (tid & 7) * 16;
      const float* src = W + (size_t)(k0 + kk) * ldw + col0 + cq;
      #pragma unroll
      for (int i = 0; i < 4; ++i)
        *(float4*)&Bt[kk][cq + 4 * i] = *(const float4*)(src + 4 * i);
    }
    __syncthreads();
    #pragma unroll
    for (int k = 0; k < 32; ++k) {
      float a[8], b[8];
      *(float4*)&a[0] = *(const float4*)&At[k][ty * 8];
      *(float4*)&a[4] = *(const float4*)&At[k][ty * 8 + 4];
      *(float4*)&b[0] = *(const float4*)&Bt[k][tx * 8];
      *(float4*)&b[4] = *(const float4*)&Bt[k][tx * 8 + 4];
      #pragma unroll
      for (int i = 0; i < 8; ++i)
        #pragma unroll
        for (int j = 0; j < 8; ++j) acc[i][j] = fmaf(a[i], b[j], acc[i][j]);
    }
    __syncthreads();
  }

  // bias + store + per-column partial stats
  float bb[8];
  *(float4*)&bb[0] = *(const float4*)(bias + col0 + tx * 8);
  *(float4*)&bb[4] = *(const float4*)(bias + col0 + tx * 8 + 4);
  float cs[8], cq2[8];
  #pragma unroll
  for (int j = 0; j < 8; ++j) { cs[j] = 0.f; cq2[j] = 0.f; }
  #pragma unroll
  for (int i = 0; i < 8; ++i) {
    int gr = row0 + ty * 8 + i;
    if (gr < M) {
      #pragma unroll
      for (int j = 0; j < 8; ++j) {
        float v = acc[i][j] + bb[j];
        acc[i][j] = v;
        cs[j] += v;
        cq2[j] += v * v;
      }
      *(float4*)(Y + (size_t)gr * ldy + col0 + tx * 8) = *(float4*)&acc[i][0];
      *(float4*)(Y + (size_t)gr * ldy + col0 + tx * 8 + 4) = *(float4*)&acc[i][4];
    }
  }
  // block-level column reduction over ty (reuse At as scratch: 2048 floats)
  float* red = &At[0][0];
  #pragma unroll
  for (int j = 0; j < 8; ++j) red[ty * 128 + tx * 8 + j] = cs[j];
  __syncthreads();
  for (int s = 8; s >= 1; s >>= 1) {
    if (ty < s) {
      #pragma unroll
      for (int j = 0; j < 8; ++j)
        red[ty * 128 + tx * 8 + j] += red[(ty + s) * 128 + tx * 8 + j];
    }
    __syncthreads();
  }
  if (ty == 0) {
    #pragma unroll
    for (int j = 0; j < 8; ++j)
      atomicAdd(&colsum[col0 + tx * 8 + j], red[tx * 8 + j]);
  }
  __syncthreads();
  #pragma unroll
  for (int j = 0; j < 8; ++j) red[ty * 128 + tx * 8 + j] = cq2[j];
  __syncthreads();
  for (int s = 8; s >= 1; s >>= 1) {
    if (ty < s) {
      #pragma unroll
      for (int j = 0; j < 8; ++j)
        red[ty * 128 + tx * 8 + j] += red[(ty + s) * 128 + tx * 8 + j];
    }
    __syncthreads();
  }
  if (ty == 0) {
    #pragma unroll
    for (int j = 0; j < 8; ++j)
      atomicAdd(&colsq[col0 + tx * 8 + j], red[tx * 8 + j]);
  }
}

// scale = g*rsqrt(var+1e-5); shift = b - mu*scale
__global__ void k_bnfin(const float* __restrict__ sum, const float* __restrict__ sq,
                        const float* __restrict__ gam, const float* __restrict__ bet,
                        float invM, int C, float* __restrict__ scale,
                        float* __restrict__ shift) {
  int c = blockIdx.x * blockDim.x + threadIdx.x;
  if (c >= C) return;
  float mu = sum[c] * invM;
  float var = sq[c] * invM - mu * mu;
  float sc = gam[c] * rsqrtf(var + 1e-5f);
  scale[c] = sc;
  shift[c] = bet[c] - mu * sc;
}

// ---------------- graph pooling (block per graph; batch is sorted) ----------------

DEV void k_pool(const float* __restrict__ hv, const int* __restrict__ batch,
                const float* __restrict__ vn, float* __restrict__ vt) {
  int g = blockIdx.x;
  int lo = 0, hi = NN;
  while (lo < hi) { int mid = (lo + hi) >> 1; if (batch[mid] < g) lo = mid + 1; else hi = mid; }
  int s = lo;
  hi = NN;
  while (lo < hi) { int mid = (lo + hi) >> 1; if (batch[mid] < g + 1) lo = mid + 1; else hi = mid; }
  int e = lo;
  int ry = threadIdx.x >> 5, cx = threadIdx.x & 31;
  float4 acc = make_float4(0.f, 0.f, 0.f, 0.f);
  for (int n = s + ry; n < e; n += 8) {
    float4 v = *(const float4*)(hv + (size_t)n * D + cx * 4);
    acc.x += v.x; acc.y += v.y; acc.z += v.z; acc.w += v.w;
  }
  __shared__ float4 red[8][32];
  red[ry][cx] = acc;
  __syncthreads();
  for (int st = 4; st >= 1; st >>= 1) {
    if (ry < st) {
      float4 o = red[ry + st][cx];
      red[ry][cx].x += o.x; red[ry][cx].y += o.y;
      red[ry][cx].z += o.z; red[ry][cx].w += o.w;
    }
    __syncthreads();
  }
  if (ry == 0) {
    float4 v = red[0][cx];
    float4 b = *(const float4*)(vn + (size_t)g * D + cx * 4);
    v.x += b.x; v.y += b.y; v.z += b.z; v.w += b.w;
    *(float4*)(vt + (size_t)g * D + cx * 4) = v;
  }
}

// ---------------- launcher ----------------

extern "C" void kernel_launch(void* const* d_in, const int* in_sizes, int n_in,
                              void* d_out, int out_size, void* d_ws, size_t ws_size,
                              hipStream_t stream) {
  const int* x = (const int*)d_in[0];
  const int* ei = (const int*)d_in[1];
  const int* eattr = (const int*)d_in[2];
  const int* batch = (const int*)d_in[3];
  const float* atom_emb = (const float*)d_in[4];
  const float* bond_emb = (const float*)d_in[5];
  const float* eps = (const float*)d_in[6];
  const float* conv_w1 = (const float*)d_in[7];
  const float* conv_b1 = (const float*)d_in[8];
  const float* conv_bn_g = (const float*)d_in[9];
  const float* conv_bn_b = (const float*)d_in[10];
  const float* conv_w2 = (const float*)d_in[11];
  const float* conv_b2 = (const float*)d_in[12];
  const float* bn_g = (const float*)d_in[13];
  const float* bn_b = (const float*)d_in[14];
  const float* vn_emb = (const float*)d_in[15];
  const float* vn_w1 = (const float*)d_in[16];
  const float* vn_b1 = (const float*)d_in[17];
  const float* vn_bn1_g = (const float*)d_in[18];
  const float* vn_bn1_b = (const float*)d_in[19];
  const float* vn_w2 = (const float*)d_in[20];
  const float* vn_b2 = (const float*)d_in[21];
  const float* vn_bn2_g = (const float*)d_in[22];
  const float* vn_bn2_b = (const float*)d_in[23];
  float* out = (float*)d_out;

  char* w = (char*)d_ws;
  auto alloc = [&](size_t bytes) {
    char* p = w;
    w += (bytes + 255) & ~((size_t)255);
    return p;
  };
  float* h   = (float*)alloc((size_t)NN * D * 4);
  float* hv  = (float*)alloc((size_t)NN * D * 4);
  float* agg = (float*)alloc((size_t)NN * D * 4);
  float* y   = (float*)alloc((size_t)NN * 256 * 4);
  float* vn  = (float*)alloc((size_t)NG * D * 4);
  float* vt  = (float*)alloc((size_t)NG * D * 4);
  float* yv  = (float*)alloc((size_t)NG * 256 * 4);
  float* zv  = (float*)alloc((size_t)NG * D * 4);
  float* stA = (float*)alloc(1024 * 4);  // sum,sq,scale,shift (256 each)
  float* sumA = stA, *sqA = stA + 256, *scaleA = stA + 512, *shiftA = stA + 768;
  float* stB = (float*)alloc(1024 * 4);
  float* sumB = stB, *sqB = stB + 256, *scaleB = stB + 512, *shiftB = stB + 768;
  int* cnt = (int*)alloc((size_t)NN * 4);
  int* rowptr = (int*)alloc((size_t)(NN + 1) * 4);
  int* cursor = (int*)alloc((size_t)NN * 4);
  unsigned* csr = (unsigned*)alloc((size_t)NE * 4);
  int* bsum = (int*)alloc(128 * 4);

  // encoders + vn init
  k_atom<<<(NN * 32 + 255) / 256, 256, 0, stream>>>(x, atom_emb, h);
  k_vninit<<<(NG * 32 + 255) / 256, 256, 0, stream>>>(vn_emb, vn);

  // CSR build (reused by all 3 layers)
  hipMemsetAsync(cnt, 0, (size_t)NN * 4, stream);
  k_hist<<<(NE + 255) / 256, 256, 0, stream>>>(ei, cnt);
  k_scan_a<<<NBLK, SCAN_B, 0, stream>>>(cnt, rowptr, bsum);
  k_scan_b<<<1, 64, 0, stream>>>(bsum, NBLK);
  k_scan_c<<<NBLK, SCAN_B, 0, stream>>>(rowptr, bsum);
  hipMemcpyAsync(cursor, rowptr, (size_t)NN * 4, hipMemcpyDeviceToDevice, stream);
  k_fill<<<(NE + 255) / 256, 256, 0, stream>>>(ei, eattr, cursor, csr);

  const int gx = (NN + 127) / 128;  // 391
  for (int l = 0; l < NL; ++l) {
    k_hv<<<(NN * 32 + 255) / 256, 256, 0, stream>>>(h, vn, batch, hv);
    k_agg<<<(NN * 64 + 255) / 256, 256, 0, stream>>>(
        hv, csr, rowptr, bond_emb + (size_t)l * 3 * 8 * D, agg);

    hipMemsetAsync(sumA, 0, 512 * 4, stream);
    k_gemm<128, 1><<<dim3(gx, 2), 256, 0, stream>>>(
        NN, hv, agg, eps + l, nullptr, nullptr, conv_w1 + (size_t)l * 128 * 256,
        256, conv_b1 + l * 256, y, 256, sumA, sqA);
    k_bnfin<<<1, 256, 0, stream>>>(sumA, sqA, conv_bn_g + l * 256,
                                   conv_bn_b + l * 256, 1.f / NN, 256, scaleA, shiftA);
    hipMemsetAsync(sumB, 0, 512 * 4, stream);
    k_gemm<256, 2><<<dim3(gx, 1), 256, 0, stream>>>(
        NN, y, nullptr, nullptr, scaleA, shiftA, conv_w2 + (size_t)l * 256 * 128,
        128, conv_b2 + l * 128, h, 128, sumB, sqB);
    k_bnfin<<<1, 256, 0, stream>>>(sumB, sqB, bn_g + l * 128, bn_b + l * 128,
                                   1.f / NN, 128, scaleB, shiftB);
    // hn = bn(z) (+relu if not last); last layer writes final output
    k_affine<<<(NN * 32 + 255) / 256, 256, 0, stream>>>(
        h, scaleB, shiftB, (l < NL - 1) ? h : out, NN, (l < NL - 1) ? 1 : 0);

    if (l < NL - 1) {
      k_pool<<<NG, 256, 0, stream>>>(hv, batch, vn, vt);
      hipMemsetAsync(sumA, 0, 512 * 4, stream);
      k_gemm<128, 0><<<dim3((NG + 127) / 128, 2), 256, 0, stream>>>(
          NG, vt, nullptr, nullptr, nullptr, nullptr,
          vn_w1 + (size_t)l * 128 * 256, 256, vn_b1 + l * 256, yv, 256, sumA, sqA);
      k_bnfin<<<1, 256, 0, stream>>>(sumA, sqA, vn_bn1_g + l * 256,
                                     vn_bn1_b + l * 256, 1.f / NG, 256, scaleA, shiftA);
      hipMemsetAsync(sumB, 0, 512 * 4, stream);
      k_gemm<256, 2><<<dim3((NG + 127) / 128, 1), 256, 0, stream>>>(
          NG, yv, nullptr, nullptr, scaleA, shiftA,
          vn_w2 + (size_t)l * 256 * 128, 128, vn_b2 + l * 128, zv, 128, sumB, sqB);
      k_bnfin<<<1, 256, 0, stream>>>(sumB, sqB, vn_bn2_g + l * 128,
                                     vn_bn2_b + l * 128, 1.f / NG, 128, scaleB, shiftB);
      k_affine<<<(NG * 32 + 255) / 256, 256, 0, stream>>>(zv, scaleB, shiftB, vn, NG, 1);
    }
  }
}

// Round 2
// 1104.649 us; speedup vs baseline: 1.4336x; 1.4336x over previous
//
#include <hip/hip_runtime.h>

#define DEV __global__ __launch_bounds__(256)

constexpr int NN = 50000;   // nodes
constexpr int NE = 600000;  // edges
constexpr int D  = 128;     // emb dim
constexpr int NG = 500;     // graphs
constexpr int NL = 3;       // layers
constexpr int SCAN_B = 512;
constexpr int NBLK = (NN + SCAN_B - 1) / SCAN_B;  // 98

typedef __attribute__((ext_vector_type(8))) short bf16x8;
typedef __attribute__((ext_vector_type(4))) float f32x4;

__device__ inline ushort f2bf(float f) {
  unsigned u = __builtin_bit_cast(unsigned, f);
  unsigned r = u + 0x7FFFu + ((u >> 16) & 1u);
  return (ushort)(r >> 16);
}
__device__ inline float bf2f(ushort h) {
  unsigned u = ((unsigned)h) << 16;
  return __builtin_bit_cast(float, u);
}

// ---------------- encoders / elementwise ----------------

DEV void k_atom(const int* __restrict__ x, const float* __restrict__ emb,
                float* __restrict__ h) {
  int t = blockIdx.x * 256 + threadIdx.x;
  int n = t >> 5, c = (t & 31) * 4;
  if (n >= NN) return;
  float4 acc = make_float4(0.f, 0.f, 0.f, 0.f);
  #pragma unroll
  for (int i = 0; i < 9; ++i) {
    int v = x[n * 9 + i];
    float4 e = *(const float4*)(emb + ((size_t)(i * 128 + v)) * D + c);
    acc.x += e.x; acc.y += e.y; acc.z += e.z; acc.w += e.w;
  }
  *(float4*)(h + (size_t)n * D + c) = acc;
}

DEV void k_vninit(const float* __restrict__ src, float* __restrict__ vn) {
  int t = blockIdx.x * 256 + threadIdx.x;
  int g = t >> 5, c = (t & 31) * 4;
  if (g >= NG) return;
  *(float4*)(vn + (size_t)g * D + c) = *(const float4*)(src + c);
}

// hv = h + vn[batch]
DEV void k_hv(const float* __restrict__ h, const float* __restrict__ vn,
              const int* __restrict__ batch, float* __restrict__ hv) {
  int t = blockIdx.x * 256 + threadIdx.x;
  int n = t >> 5, c = (t & 31) * 4;
  if (n >= NN) return;
  float4 a = *(const float4*)(h + (size_t)n * D + c);
  float4 b = *(const float4*)(vn + (size_t)batch[n] * D + c);
  a.x += b.x; a.y += b.y; a.z += b.z; a.w += b.w;
  *(float4*)(hv + (size_t)n * D + c) = a;
}

// out = z*scale[c]+shift[c] (+relu)
DEV void k_affine(const float* __restrict__ z, const float* __restrict__ scale,
                  const float* __restrict__ shift, float* __restrict__ outp,
                  int M, int relu) {
  int t = blockIdx.x * 256 + threadIdx.x;
  int n = t >> 5, c = (t & 31) * 4;
  if (n >= M) return;
  float4 v = *(const float4*)(z + (size_t)n * 128 + c);
  float4 sc = *(const float4*)(scale + c);
  float4 sh = *(const float4*)(shift + c);
  v.x = fmaf(v.x, sc.x, sh.x);
  v.y = fmaf(v.y, sc.y, sh.y);
  v.z = fmaf(v.z, sc.z, sh.z);
  v.w = fmaf(v.w, sc.w, sh.w);
  if (relu) {
    v.x = fmaxf(v.x, 0.f); v.y = fmaxf(v.y, 0.f);
    v.z = fmaxf(v.z, 0.f); v.w = fmaxf(v.w, 0.f);
  }
  *(float4*)(outp + (size_t)n * 128 + c) = v;
}

// ---------------- CSR build ----------------

DEV void k_hist(const int* __restrict__ ei, int* __restrict__ cnt) {
  int e = blockIdx.x * 256 + threadIdx.x;
  if (e < NE) atomicAdd(&cnt[ei[NE + e]], 1);
}

__global__ __launch_bounds__(SCAN_B) void k_scan_a(const int* __restrict__ cnt,
                                                   int* __restrict__ rowptr,
                                                   int* __restrict__ bsum) {
  __shared__ int sh[SCAN_B];
  int i = blockIdx.x * SCAN_B + threadIdx.x;
  int v = (i < NN) ? cnt[i] : 0;
  sh[threadIdx.x] = v;
  __syncthreads();
  for (int off = 1; off < SCAN_B; off <<= 1) {
    int u = (threadIdx.x >= (unsigned)off) ? sh[threadIdx.x - off] : 0;
    __syncthreads();
    sh[threadIdx.x] += u;
    __syncthreads();
  }
  if (i < NN) rowptr[i + 1] = sh[threadIdx.x];
  if (threadIdx.x == SCAN_B - 1) bsum[blockIdx.x] = sh[SCAN_B - 1];
}

__global__ void k_scan_b(int* __restrict__ bsum, int nb) {
  if (threadIdx.x == 0 && blockIdx.x == 0) {
    int acc = 0;
    for (int i = 0; i < nb; ++i) { int v = bsum[i]; bsum[i] = acc; acc += v; }
  }
}

__global__ __launch_bounds__(SCAN_B) void k_scan_c(int* __restrict__ rowptr,
                                                   const int* __restrict__ bsum) {
  int i = blockIdx.x * SCAN_B + threadIdx.x;
  if (i < NN) rowptr[i + 1] += bsum[blockIdx.x];
  if (i == 0) rowptr[0] = 0;
}

DEV void k_fill(const int* __restrict__ ei, const int* __restrict__ eattr,
                int* __restrict__ cursor, unsigned* __restrict__ csr) {
  int e = blockIdx.x * 256 + threadIdx.x;
  if (e >= NE) return;
  int dn = ei[NE + e];
  int p = atomicAdd(&cursor[dn], 1);
  unsigned a0 = (unsigned)eattr[e * 3 + 0];
  unsigned a1 = (unsigned)eattr[e * 3 + 1];
  unsigned a2 = (unsigned)eattr[e * 3 + 2];
  csr[p] = (unsigned)ei[e] | (a0 << 17) | (a1 << 20) | (a2 << 23);
}

// ---------------- edge aggregation (wave per node, no atomics) ----------------

DEV void k_agg(const float* __restrict__ hv, const unsigned* __restrict__ csr,
               const int* __restrict__ rowptr, const float* __restrict__ bond,
               float* __restrict__ agg) {
  __shared__ float eb[3 * 8 * D];
  for (int i = threadIdx.x; i < 3 * 8 * D; i += 256) eb[i] = bond[i];
  __syncthreads();
  int wid = (blockIdx.x * 256 + threadIdx.x) >> 6;
  int lane = threadIdx.x & 63;
  if (wid >= NN) return;
  int d0 = lane * 2;
  float ax = 0.f, ay = 0.f;
  int p1 = rowptr[wid + 1];
  for (int p = rowptr[wid]; p < p1; ++p) {
    unsigned pk = csr[p];
    int s = pk & 0x1FFFF;
    float2 hvv = *(const float2*)(hv + (size_t)s * D + d0);
    float2 e0 = *(const float2*)(eb + (((pk >> 17) & 7u)) * D + d0);
    float2 e1 = *(const float2*)(eb + (8 + ((pk >> 20) & 7u)) * D + d0);
    float2 e2 = *(const float2*)(eb + (16 + ((pk >> 23) & 7u)) * D + d0);
    float mx = hvv.x + e0.x + e1.x + e2.x;
    float my = hvv.y + e0.y + e1.y + e2.y;
    ax += fmaxf(mx, 0.f);
    ay += fmaxf(my, 0.f);
  }
  *(float2*)(agg + (size_t)wid * D + d0) = make_float2(ax, ay);
}

// ---------------- weight transpose + bf16 hi/lo split ----------------
// src fp32 [L][K][NC] -> th/tl bf16 [L][NC][K]
__global__ __launch_bounds__(256) void k_cvtw(const float* __restrict__ src, int K,
                                              int lognc, ushort* __restrict__ th,
                                              ushort* __restrict__ tl) {
  int NC = 1 << lognc;
  size_t base = (size_t)blockIdx.y * K * NC;
  int i = blockIdx.x * 256 + threadIdx.x;
  if (i >= K * NC) return;
  int k = i >> lognc, c = i & (NC - 1);
  float v = src[base + i];
  ushort hi = f2bf(v);
  th[base + (size_t)c * K + k] = hi;
  tl[base + (size_t)c * K + k] = f2bf(v - bf2f(hi));
}

// ---------------- MFMA bf16x3 GEMM + BN-stats epilogue ----------------
// Y[:, col0:col0+128] = A' @ Wt^T + bias
//   AMODE 1: A' = (1+*epsp)*A0 + A1        (A0,A1 fp32 [M][K])
//   AMODE 2: A' = relu(A0*ascale[k]+ashift[k])
// Wt bf16 hi/lo, [NC][K] (pre-transposed). fp32 accumulate via 3-term MFMA.
template <int AMODE>
__global__ __launch_bounds__(256) void k_mgemm(
    int M, int K, const float* __restrict__ A0, const float* __restrict__ A1,
    const float* __restrict__ epsp, const float* __restrict__ ascale,
    const float* __restrict__ ashift, const ushort* __restrict__ Wth,
    const ushort* __restrict__ Wtl, const float* __restrict__ bias,
    float* __restrict__ Y, int ldy, float* __restrict__ colsum,
    float* __restrict__ colsq) {
  // fragment-major LDS: [kchunk][row][8 bf16] -> all ds accesses lane-consecutive
  __shared__ __align__(16) ushort Ah[4][128][8];
  __shared__ __align__(16) ushort Al[4][128][8];
  __shared__ __align__(16) ushort Bh[4][128][8];
  __shared__ __align__(16) ushort Bl[4][128][8];
  const int tid = threadIdx.x;
  const int row0 = blockIdx.x * 128, col0 = blockIdx.y * 128;
  const int lane = tid & 63, w = tid >> 6;
  const int wr = w >> 1, wc = w & 1;    // wave tile: 64x64
  const int kc = lane >> 4, lr = lane & 15;
  const int sr = tid & 127, sc0 = (tid >> 7) * 2;  // staging row / chunk base

  float ef = 0.f;
  if (AMODE == 1) ef = 1.f + *epsp;
  f32x4 acc[4][4] = {};

  for (int k0 = 0; k0 < K; k0 += 32) {
    // ---- stage A' (with fused prologue + hi/lo split) and B ----
    #pragma unroll
    for (int cc = 0; cc < 2; ++cc) {
      const int c = sc0 + cc;
      const int gk = k0 + c * 8;
      const int gr = row0 + sr;
      float v[8];
      if (gr < M) {
        f32x4 a0 = *(const f32x4*)(A0 + (size_t)gr * K + gk);
        f32x4 a1 = *(const f32x4*)(A0 + (size_t)gr * K + gk + 4);
        if (AMODE == 1) {
          f32x4 g0 = *(const f32x4*)(A1 + (size_t)gr * K + gk);
          f32x4 g1 = *(const f32x4*)(A1 + (size_t)gr * K + gk + 4);
          #pragma unroll
          for (int j = 0; j < 4; ++j) {
            v[j] = fmaf(ef, a0[j], g0[j]);
            v[4 + j] = fmaf(ef, a1[j], g1[j]);
          }
        } else if (AMODE == 2) {
          f32x4 s0 = *(const f32x4*)(ascale + gk);
          f32x4 s1 = *(const f32x4*)(ascale + gk + 4);
          f32x4 t0 = *(const f32x4*)(ashift + gk);
          f32x4 t1 = *(const f32x4*)(ashift + gk + 4);
          #pragma unroll
          for (int j = 0; j < 4; ++j) {
            v[j] = fmaxf(fmaf(a0[j], s0[j], t0[j]), 0.f);
            v[4 + j] = fmaxf(fmaf(a1[j], s1[j], t1[j]), 0.f);
          }
        } else {
          #pragma unroll
          for (int j = 0; j < 4; ++j) { v[j] = a0[j]; v[4 + j] = a1[j]; }
        }
      } else {
        #pragma unroll
        for (int j = 0; j < 8; ++j) v[j] = 0.f;
      }
      alignas(16) ushort th[8], tl[8];
      #pragma unroll
      for (int j = 0; j < 8; ++j) {
        ushort hi = f2bf(v[j]);
        th[j] = hi;
        tl[j] = f2bf(v[j] - bf2f(hi));
      }
      *(uint4*)&Ah[c][sr][0] = *(const uint4*)th;
      *(uint4*)&Al[c][sr][0] = *(const uint4*)tl;
      // B: rows of Wt (= cols of W), already bf16 hi/lo, contiguous in K
      *(uint4*)&Bh[c][sr][0] = *(const uint4*)(Wth + (size_t)(col0 + sr) * K + gk);
      *(uint4*)&Bl[c][sr][0] = *(const uint4*)(Wtl + (size_t)(col0 + sr) * K + gk);
    }
    __syncthreads();
    // ---- MFMA: 3-term bf16 emulation of fp32 ----
    bf16x8 bhf[4], blf[4];
    #pragma unroll
    for (int fc = 0; fc < 4; ++fc) {
      bhf[fc] = *(const bf16x8*)&Bh[kc][wc * 64 + fc * 16 + lr][0];
      blf[fc] = *(const bf16x8*)&Bl[kc][wc * 64 + fc * 16 + lr][0];
    }
    #pragma unroll
    for (int fr = 0; fr < 4; ++fr) {
      bf16x8 ahf = *(const bf16x8*)&Ah[kc][wr * 64 + fr * 16 + lr][0];
      bf16x8 alf = *(const bf16x8*)&Al[kc][wr * 64 + fr * 16 + lr][0];
      #pragma unroll
      for (int fc = 0; fc < 4; ++fc) {
        acc[fr][fc] = __builtin_amdgcn_mfma_f32_16x16x32_bf16(ahf, bhf[fc], acc[fr][fc], 0, 0, 0);
        acc[fr][fc] = __builtin_amdgcn_mfma_f32_16x16x32_bf16(alf, bhf[fc], acc[fr][fc], 0, 0, 0);
        acc[fr][fc] = __builtin_amdgcn_mfma_f32_16x16x32_bf16(ahf, blf[fc], acc[fr][fc], 0, 0, 0);
      }
    }
    __syncthreads();
  }

  // ---- epilogue: bias, store, per-column stats ----
  #pragma unroll
  for (int fc = 0; fc < 4; ++fc) {
    const int gc = col0 + wc * 64 + fc * 16 + lr;
    const float bb = bias[gc];
    float cs = 0.f, cq = 0.f;
    #pragma unroll
    for (int fr = 0; fr < 4; ++fr) {
      const int rb = row0 + wr * 64 + fr * 16 + kc * 4;
      #pragma unroll
      for (int rg = 0; rg < 4; ++rg) {
        int gr = rb + rg;
        if (gr < M) {
          float v = acc[fr][fc][rg] + bb;
          Y[(size_t)gr * ldy + gc] = v;
          cs += v;
          cq += v * v;
        }
      }
    }
    cs += __shfl_xor(cs, 16); cs += __shfl_xor(cs, 32);
    cq += __shfl_xor(cq, 16); cq += __shfl_xor(cq, 32);
    if (kc == 0) {
      atomicAdd(&colsum[gc], cs);
      atomicAdd(&colsq[gc], cq);
    }
  }
}

// ---------------- fp32 GEMM (kept for tiny vn MLPs, M=500) ----------------
template <int KT, int AMODE>
__global__ __launch_bounds__(256) void k_gemm(
    int M, const float* __restrict__ A0, const float* __restrict__ A1,
    const float* __restrict__ epsp, const float* __restrict__ ascale,
    const float* __restrict__ ashift, const float* __restrict__ W, int ldw,
    const float* __restrict__ bias, float* __restrict__ Y, int ldy,
    float* __restrict__ colsum, float* __restrict__ colsq) {
  __shared__ float At[32][132];
  __shared__ float Bt[32][132];
  const int tid = threadIdx.x;
  const int tx = tid & 15, ty = tid >> 4;
  const int row0 = blockIdx.x * 128, col0 = blockIdx.y * 128;
  float acc[8][8];
  #pragma unroll
  for (int i = 0; i < 8; ++i)
    #pragma unroll
    for (int j = 0; j < 8; ++j) acc[i][j] = 0.f;
  float ef = 0.f;
  if (AMODE == 1) ef = 1.f + *epsp;

  for (int k0 = 0; k0 < KT; k0 += 32) {
    {
      const int r_ = tid >> 3;
      const int kq = (tid & 7) * 4;
      #pragma unroll
      for (int i = 0; i < 4; ++i) {
        int r = r_ + 32 * i;
        int gr = row0 + r;
        float4 v = make_float4(0.f, 0.f, 0.f, 0.f);
        if (gr < M) {
          v = *(const float4*)(A0 + (size_t)gr * KT + k0 + kq);
          if (AMODE == 1) {
            float4 g = *(const float4*)(A1 + (size_t)gr * KT + k0 + kq);
            v.x = fmaf(ef, v.x, g.x); v.y = fmaf(ef, v.y, g.y);
            v.z = fmaf(ef, v.z, g.z); v.w = fmaf(ef, v.w, g.w);
          } else if (AMODE == 2) {
            int kk = k0 + kq;
            v.x = fmaxf(fmaf(v.x, ascale[kk + 0], ashift[kk + 0]), 0.f);
            v.y = fmaxf(fmaf(v.y, ascale[kk + 1], ashift[kk + 1]), 0.f);
            v.z = fmaxf(fmaf(v.z, ascale[kk + 2], ashift[kk + 2]), 0.f);
            v.w = fmaxf(fmaf(v.w, ascale[kk + 3], ashift[kk + 3]), 0.f);
          }
        }
        At[kq + 0][r] = v.x; At[kq + 1][r] = v.y;
        At[kq + 2][r] = v.z; At[kq + 3][r] = v.w;
      }
    }
    {
      const int kk = tid >> 3;
      const int cq = (tid & 7) * 16;
      const float* src = W + (size_t)(k0 + kk) * ldw + col0 + cq;
      #pragma unroll
      for (int i = 0; i < 4; ++i)
        *(float4*)&Bt[kk][cq + 4 * i] = *(const float4*)(src + 4 * i);
    }
    __syncthreads();
    #pragma unroll
    for (int k = 0; k < 32; ++k) {
      float a[8], b[8];
      *(float4*)&a[0] = *(const float4*)&At[k][ty * 8];
      *(float4*)&a[4] = *(const float4*)&At[k][ty * 8 + 4];
      *(float4*)&b[0] = *(const float4*)&Bt[k][tx * 8];
      *(float4*)&b[4] = *(const float4*)&Bt[k][tx * 8 + 4];
      #pragma unroll
      for (int i = 0; i < 8; ++i)
        #pragma unroll
        for (int j = 0; j < 8; ++j) acc[i][j] = fmaf(a[i], b[j], acc[i][j]);
    }
    __syncthreads();
  }

  float bb[8];
  *(float4*)&bb[0] = *(const float4*)(bias + col0 + tx * 8);
  *(float4*)&bb[4] = *(const float4*)(bias + col0 + tx * 8 + 4);
  float cs[8], cq2[8];
  #pragma unroll
  for (int j = 0; j < 8; ++j) { cs[j] = 0.f; cq2[j] = 0.f; }
  #pragma unroll
  for (int i = 0; i < 8; ++i) {
    int gr = row0 + ty * 8 + i;
    if (gr < M) {
      #pragma unroll
      for (int j = 0; j < 8; ++j) {
        float v = acc[i][j] + bb[j];
        acc[i][j] = v;
        cs[j] += v;
        cq2[j] += v * v;
      }
      *(float4*)(Y + (size_t)gr * ldy + col0 + tx * 8) = *(float4*)&acc[i][0];
      *(float4*)(Y + (size_t)gr * ldy + col0 + tx * 8 + 4) = *(float4*)&acc[i][4];
    }
  }
  float* red = &At[0][0];
  #pragma unroll
  for (int j = 0; j < 8; ++j) red[ty * 128 + tx * 8 + j] = cs[j];
  __syncthreads();
  for (int s = 8; s >= 1; s >>= 1) {
    if (ty < s) {
      #pragma unroll
      for (int j = 0; j < 8; ++j)
        red[ty * 128 + tx * 8 + j] += red[(ty + s) * 128 + tx * 8 + j];
    }
    __syncthreads();
  }
  if (ty == 0) {
    #pragma unroll
    for (int j = 0; j < 8; ++j)
      atomicAdd(&colsum[col0 + tx * 8 + j], red[tx * 8 + j]);
  }
  __syncthreads();
  #pragma unroll
  for (int j = 0; j < 8; ++j) red[ty * 128 + tx * 8 + j] = cq2[j];
  __syncthreads();
  for (int s = 8; s >= 1; s >>= 1) {
    if (ty < s) {
      #pragma unroll
      for (int j = 0; j < 8; ++j)
        red[ty * 128 + tx * 8 + j] += red[(ty + s) * 128 + tx * 8 + j];
    }
    __syncthreads();
  }
  if (ty == 0) {
    #pragma unroll
    for (int j = 0; j < 8; ++j)
      atomicAdd(&colsq[col0 + tx * 8 + j], red[tx * 8 + j]);
  }
}

__global__ void k_bnfin(const float* __restrict__ sum, const float* __restrict__ sq,
                        const float* __restrict__ gam, const float* __restrict__ bet,
                        float invM, int C, float* __restrict__ scale,
                        float* __restrict__ shift) {
  int c = blockIdx.x * blockDim.x + threadIdx.x;
  if (c >= C) return;
  float mu = sum[c] * invM;
  float var = sq[c] * invM - mu * mu;
  float sc = gam[c] * rsqrtf(var + 1e-5f);
  scale[c] = sc;
  shift[c] = bet[c] - mu * sc;
}

// ---------------- graph pooling ----------------

DEV void k_pool(const float* __restrict__ hv, const int* __restrict__ batch,
                const float* __restrict__ vn, float* __restrict__ vt) {
  int g = blockIdx.x;
  int lo = 0, hi = NN;
  while (lo < hi) { int mid = (lo + hi) >> 1; if (batch[mid] < g) lo = mid + 1; else hi = mid; }
  int s = lo;
  hi = NN;
  while (lo < hi) { int mid = (lo + hi) >> 1; if (batch[mid] < g + 1) lo = mid + 1; else hi = mid; }
  int e = lo;
  int ry = threadIdx.x >> 5, cx = threadIdx.x & 31;
  float4 acc = make_float4(0.f, 0.f, 0.f, 0.f);
  for (int n = s + ry; n < e; n += 8) {
    float4 v = *(const float4*)(hv + (size_t)n * D + cx * 4);
    acc.x += v.x; acc.y += v.y; acc.z += v.z; acc.w += v.w;
  }
  __shared__ float4 red[8][32];
  red[ry][cx] = acc;
  __syncthreads();
  for (int st = 4; st >= 1; st >>= 1) {
    if (ry < st) {
      float4 o = red[ry + st][cx];
      red[ry][cx].x += o.x; red[ry][cx].y += o.y;
      red[ry][cx].z += o.z; red[ry][cx].w += o.w;
    }
    __syncthreads();
  }
  if (ry == 0) {
    float4 v = red[0][cx];
    float4 b = *(const float4*)(vn + (size_t)g * D + cx * 4);
    v.x += b.x; v.y += b.y; v.z += b.z; v.w += b.w;
    *(float4*)(vt + (size_t)g * D + cx * 4) = v;
  }
}

// ---------------- launcher ----------------

extern "C" void kernel_launch(void* const* d_in, const int* in_sizes, int n_in,
                              void* d_out, int out_size, void* d_ws, size_t ws_size,
                              hipStream_t stream) {
  const int* x = (const int*)d_in[0];
  const int* ei = (const int*)d_in[1];
  const int* eattr = (const int*)d_in[2];
  const int* batch = (const int*)d_in[3];
  const float* atom_emb = (const float*)d_in[4];
  const float* bond_emb = (const float*)d_in[5];
  const float* eps = (const float*)d_in[6];
  const float* conv_w1 = (const float*)d_in[7];
  const float* conv_b1 = (const float*)d_in[8];
  const float* conv_bn_g = (const float*)d_in[9];
  const float* conv_bn_b = (const float*)d_in[10];
  const float* conv_w2 = (const float*)d_in[11];
  const float* conv_b2 = (const float*)d_in[12];
  const float* bn_g = (const float*)d_in[13];
  const float* bn_b = (const float*)d_in[14];
  const float* vn_emb = (const float*)d_in[15];
  const float* vn_w1 = (const float*)d_in[16];
  const float* vn_b1 = (const float*)d_in[17];
  const float* vn_bn1_g = (const float*)d_in[18];
  const float* vn_bn1_b = (const float*)d_in[19];
  const float* vn_w2 = (const float*)d_in[20];
  const float* vn_b2 = (const float*)d_in[21];
  const float* vn_bn2_g = (const float*)d_in[22];
  const float* vn_bn2_b = (const float*)d_in[23];
  float* out = (float*)d_out;

  char* w = (char*)d_ws;
  auto alloc = [&](size_t bytes) {
    char* p = w;
    w += (bytes + 255) & ~((size_t)255);
    return p;
  };
  float* h   = (float*)alloc((size_t)NN * D * 4);
  float* hv  = (float*)alloc((size_t)NN * D * 4);
  float* agg = (float*)alloc((size_t)NN * D * 4);
  float* y   = (float*)alloc((size_t)NN * 256 * 4);
  float* vn  = (float*)alloc((size_t)NG * D * 4);
  float* vt  = (float*)alloc((size_t)NG * D * 4);
  float* yv  = (float*)alloc((size_t)NG * 256 * 4);
  float* zv  = (float*)alloc((size_t)NG * D * 4);
  float* stA = (float*)alloc(1024 * 4);
  float* sumA = stA, *sqA = stA + 256, *scaleA = stA + 512, *shiftA = stA + 768;
  float* stB = (float*)alloc(1024 * 4);
  float* sumB = stB, *sqB = stB + 256, *scaleB = stB + 512, *shiftB = stB + 768;
  int* cnt = (int*)alloc((size_t)NN * 4);
  int* rowptr = (int*)alloc((size_t)(NN + 1) * 4);
  int* cursor = (int*)alloc((size_t)NN * 4);
  unsigned* csr = (unsigned*)alloc((size_t)NE * 4);
  int* bsum = (int*)alloc(128 * 4);
  ushort* wt1h = (ushort*)alloc((size_t)NL * 256 * 128 * 2);
  ushort* wt1l = (ushort*)alloc((size_t)NL * 256 * 128 * 2);
  ushort* wt2h = (ushort*)alloc((size_t)NL * 128 * 256 * 2);
  ushort* wt2l = (ushort*)alloc((size_t)NL * 128 * 256 * 2);

  // weight transpose + split (all layers)
  k_cvtw<<<dim3(128, NL), 256, 0, stream>>>(conv_w1, 128, 8, wt1h, wt1l);
  k_cvtw<<<dim3(128, NL), 256, 0, stream>>>(conv_w2, 256, 7, wt2h, wt2l);

  // encoders + vn init
  k_atom<<<(NN * 32 + 255) / 256, 256, 0, stream>>>(x, atom_emb, h);
  k_vninit<<<(NG * 32 + 255) / 256, 256, 0, stream>>>(vn_emb, vn);

  // CSR build (reused by all 3 layers)
  hipMemsetAsync(cnt, 0, (size_t)NN * 4, stream);
  k_hist<<<(NE + 255) / 256, 256, 0, stream>>>(ei, cnt);
  k_scan_a<<<NBLK, SCAN_B, 0, stream>>>(cnt, rowptr, bsum);
  k_scan_b<<<1, 64, 0, stream>>>(bsum, NBLK);
  k_scan_c<<<NBLK, SCAN_B, 0, stream>>>(rowptr, bsum);
  hipMemcpyAsync(cursor, rowptr, (size_t)NN * 4, hipMemcpyDeviceToDevice, stream);
  k_fill<<<(NE + 255) / 256, 256, 0, stream>>>(ei, eattr, cursor, csr);

  const int gx = (NN + 127) / 128;  // 391
  for (int l = 0; l < NL; ++l) {
    k_hv<<<(NN * 32 + 255) / 256, 256, 0, stream>>>(h, vn, batch, hv);
    k_agg<<<(NN * 64 + 255) / 256, 256, 0, stream>>>(
        hv, csr, rowptr, bond_emb + (size_t)l * 3 * 8 * D, agg);

    hipMemsetAsync(sumA, 0, 512 * 4, stream);
    k_mgemm<1><<<dim3(gx, 2), 256, 0, stream>>>(
        NN, 128, hv, agg, eps + l, nullptr, nullptr,
        wt1h + (size_t)l * 256 * 128, wt1l + (size_t)l * 256 * 128,
        conv_b1 + l * 256, y, 256, sumA, sqA);
    k_bnfin<<<1, 256, 0, stream>>>(sumA, sqA, conv_bn_g + l * 256,
                                   conv_bn_b + l * 256, 1.f / NN, 256, scaleA, shiftA);
    hipMemsetAsync(sumB, 0, 512 * 4, stream);
    k_mgemm<2><<<dim3(gx, 1), 256, 0, stream>>>(
        NN, 256, y, nullptr, nullptr, scaleA, shiftA,
        wt2h + (size_t)l * 128 * 256, wt2l + (size_t)l * 128 * 256,
        conv_b2 + l * 128, h, 128, sumB, sqB);
    k_bnfin<<<1, 256, 0, stream>>>(sumB, sqB, bn_g + l * 128, bn_b + l * 128,
                                   1.f / NN, 128, scaleB, shiftB);
    k_affine<<<(NN * 32 + 255) / 256, 256, 0, stream>>>(
        h, scaleB, shiftB, (l < NL - 1) ? h : out, NN, (l < NL - 1) ? 1 : 0);

    if (l < NL - 1) {
      k_pool<<<NG, 256, 0, stream>>>(hv, batch, vn, vt);
      hipMemsetAsync(sumA, 0, 512 * 4, stream);
      k_gemm<128, 0><<<dim3((NG + 127) / 128, 2), 256, 0, stream>>>(
          NG, vt, nullptr, nullptr, nullptr, nullptr,
          vn_w1 + (size_t)l * 128 * 256, 256, vn_b1 + l * 256, yv, 256, sumA, sqA);
      k_bnfin<<<1, 256, 0, stream>>>(sumA, sqA, vn_bn1_g + l * 256,
                                     vn_bn1_b + l * 256, 1.f / NG, 256, scaleA, shiftA);
      hipMemsetAsync(sumB, 0, 512 * 4, stream);
      k_gemm<256, 2><<<dim3((NG + 127) / 128, 1), 256, 0, stream>>>(
          NG, yv, nullptr, nullptr, scaleA, shiftA,
          vn_w2 + (size_t)l * 256 * 128, 128, vn_b2 + l * 128, zv, 128, sumB, sqB);
      k_bnfin<<<1, 256, 0, stream>>>(sumB, sqB, vn_bn2_g + l * 128,
                                     vn_bn2_b + l * 128, 1.f / NG, 128, scaleB, shiftB);
      k_affine<<<(NG * 32 + 255) / 256, 256, 0, stream>>>(zv, scaleB, shiftB, vn, NG, 1);
    }
  }
}

// Round 5
// 874.804 us; speedup vs baseline: 1.8103x; 1.2627x over previous
//
#include <hip/hip_runtime.h>

#define DEV __global__ __launch_bounds__(256)

constexpr int NN = 50000;   // nodes
constexpr int NE = 600000;  // edges
constexpr int D  = 128;     // emb dim
constexpr int NG = 500;     // graphs
constexpr int NL = 3;       // layers
constexpr int SCAN_B = 512;
constexpr int NBLK = (NN + SCAN_B - 1) / SCAN_B;  // 98

typedef __attribute__((ext_vector_type(8))) short bf16x8;
typedef __attribute__((ext_vector_type(4))) float f32x4;

__device__ inline ushort f2bf(float f) {
  unsigned u = __builtin_bit_cast(unsigned, f);
  unsigned r = u + 0x7FFFu + ((u >> 16) & 1u);
  return (ushort)(r >> 16);
}
__device__ inline float bf2f(ushort h) {
  unsigned u = ((unsigned)h) << 16;
  return __builtin_bit_cast(float, u);
}

// ---------------- encoders / elementwise ----------------

// hv0[n][d] = sum_i atom_emb[i][x[n][i]][d] + vn_emb[d]
DEV void k_atom(const int* __restrict__ x, const float* __restrict__ emb,
                const float* __restrict__ vne, float* __restrict__ hv) {
  int t = blockIdx.x * 256 + threadIdx.x;
  int n = t >> 5, c = (t & 31) * 4;
  if (n >= NN) return;
  float4 acc = *(const float4*)(vne + c);
  #pragma unroll
  for (int i = 0; i < 9; ++i) {
    int v = x[n * 9 + i];
    float4 e = *(const float4*)(emb + ((size_t)(i * 128 + v)) * D + c);
    acc.x += e.x; acc.y += e.y; acc.z += e.z; acc.w += e.w;
  }
  *(float4*)(hv + (size_t)n * D + c) = acc;
}

DEV void k_vninit(const float* __restrict__ src, float* __restrict__ vn) {
  int t = blockIdx.x * 256 + threadIdx.x;
  int g = t >> 5, c = (t & 31) * 4;
  if (g >= NG) return;
  *(float4*)(vn + (size_t)g * D + c) = *(const float4*)(src + c);
}

// dst = bn(z) [+relu] [+ vnadd[batch]]   (stats computed inline from sum/sq)
DEV void k_post(const float* __restrict__ z, const float* __restrict__ sum,
                const float* __restrict__ sq, const float* __restrict__ gam,
                const float* __restrict__ bet, float invM,
                const float* __restrict__ vnadd, const int* __restrict__ batch,
                float* __restrict__ dst, int M, int relu) {
  int t = blockIdx.x * 256 + threadIdx.x;
  int n = t >> 5, c = (t & 31) * 4;
  if (n >= M) return;
  f32x4 s = *(const f32x4*)(sum + c);
  f32x4 q = *(const f32x4*)(sq + c);
  f32x4 g = *(const f32x4*)(gam + c);
  f32x4 b = *(const f32x4*)(bet + c);
  f32x4 v = *(const f32x4*)(z + (size_t)n * 128 + c);
  f32x4 o;
  #pragma unroll
  for (int j = 0; j < 4; ++j) {
    float mu = s[j] * invM;
    float var = q[j] * invM - mu * mu;
    float sc = g[j] * rsqrtf(var + 1e-5f);
    float sh = b[j] - mu * sc;
    o[j] = fmaf(v[j], sc, sh);
    if (relu) o[j] = fmaxf(o[j], 0.f);
  }
  if (vnadd) {
    f32x4 a = *(const f32x4*)(vnadd + (size_t)batch[n] * 128 + c);
    #pragma unroll
    for (int j = 0; j < 4; ++j) o[j] += a[j];
  }
  *(f32x4*)(dst + (size_t)n * 128 + c) = o;
}

// ---------------- CSR build ----------------

DEV void k_hist(const int* __restrict__ ei, int* __restrict__ cnt) {
  int e = blockIdx.x * 256 + threadIdx.x;
  if (e < NE) atomicAdd(&cnt[ei[NE + e]], 1);
}

__global__ __launch_bounds__(SCAN_B) void k_scan_a(const int* __restrict__ cnt,
                                                   int* __restrict__ rowptr,
                                                   int* __restrict__ bsum) {
  __shared__ int sh[SCAN_B];
  int i = blockIdx.x * SCAN_B + threadIdx.x;
  int v = (i < NN) ? cnt[i] : 0;
  sh[threadIdx.x] = v;
  __syncthreads();
  for (int off = 1; off < SCAN_B; off <<= 1) {
    int u = (threadIdx.x >= (unsigned)off) ? sh[threadIdx.x - off] : 0;
    __syncthreads();
    sh[threadIdx.x] += u;
    __syncthreads();
  }
  if (i < NN) rowptr[i + 1] = sh[threadIdx.x];
  if (threadIdx.x == SCAN_B - 1) bsum[blockIdx.x] = sh[SCAN_B - 1];
}

__global__ void k_scan_b(int* __restrict__ bsum, int nb) {
  if (threadIdx.x == 0 && blockIdx.x == 0) {
    int acc = 0;
    for (int i = 0; i < nb; ++i) { int v = bsum[i]; bsum[i] = acc; acc += v; }
  }
}

__global__ __launch_bounds__(SCAN_B) void k_scan_c(int* __restrict__ rowptr,
                                                   const int* __restrict__ bsum) {
  int i = blockIdx.x * SCAN_B + threadIdx.x;
  if (i < NN) rowptr[i + 1] += bsum[blockIdx.x];
  if (i == 0) rowptr[0] = 0;
}

DEV void k_fill(const int* __restrict__ ei, const int* __restrict__ eattr,
                int* __restrict__ cursor, unsigned* __restrict__ csr) {
  int e = blockIdx.x * 256 + threadIdx.x;
  if (e >= NE) return;
  int dn = ei[NE + e];
  int p = atomicAdd(&cursor[dn], 1);
  unsigned a0 = (unsigned)eattr[e * 3 + 0];
  unsigned a1 = (unsigned)eattr[e * 3 + 1];
  unsigned a2 = (unsigned)eattr[e * 3 + 2];
  csr[p] = (unsigned)ei[e] | (a0 << 17) | (a1 << 20) | (a2 << 23);
}

// ---------------- edge aggregation (wave per node, 4-deep pipelined) ----------------

DEV void k_agg(const float* __restrict__ hv, const unsigned* __restrict__ csr,
               const int* __restrict__ rowptr, const float* __restrict__ bond,
               float* __restrict__ agg) {
  __shared__ float eb[3 * 8 * D];
  for (int i = threadIdx.x; i < 3 * 8 * D; i += 256) eb[i] = bond[i];
  __syncthreads();
  int wid = (blockIdx.x * 256 + threadIdx.x) >> 6;
  int lane = threadIdx.x & 63;
  if (wid >= NN) return;
  int d0 = lane * 2;
  float ax = 0.f, ay = 0.f;
  int p = rowptr[wid];
  const int p1 = rowptr[wid + 1];
  for (; p + 4 <= p1; p += 4) {
    unsigned pk[4];
    #pragma unroll
    for (int j = 0; j < 4; ++j) pk[j] = csr[p + j];
    float2 hvv[4];
    #pragma unroll
    for (int j = 0; j < 4; ++j)
      hvv[j] = *(const float2*)(hv + (size_t)(pk[j] & 0x1FFFF) * D + d0);
    #pragma unroll
    for (int j = 0; j < 4; ++j) {
      float2 e0 = *(const float2*)(eb + (((pk[j] >> 17) & 7u)) * D + d0);
      float2 e1 = *(const float2*)(eb + (8 + ((pk[j] >> 20) & 7u)) * D + d0);
      float2 e2 = *(const float2*)(eb + (16 + ((pk[j] >> 23) & 7u)) * D + d0);
      ax += fmaxf(hvv[j].x + e0.x + e1.x + e2.x, 0.f);
      ay += fmaxf(hvv[j].y + e0.y + e1.y + e2.y, 0.f);
    }
  }
  for (; p < p1; ++p) {
    unsigned pk = csr[p];
    float2 hvv = *(const float2*)(hv + (size_t)(pk & 0x1FFFF) * D + d0);
    float2 e0 = *(const float2*)(eb + (((pk >> 17) & 7u)) * D + d0);
    float2 e1 = *(const float2*)(eb + (8 + ((pk >> 20) & 7u)) * D + d0);
    float2 e2 = *(const float2*)(eb + (16 + ((pk >> 23) & 7u)) * D + d0);
    ax += fmaxf(hvv.x + e0.x + e1.x + e2.x, 0.f);
    ay += fmaxf(hvv.y + e0.y + e1.y + e2.y, 0.f);
  }
  *(float2*)(agg + (size_t)wid * D + d0) = make_float2(ax, ay);
}

// ---------------- weight transpose + bf16 hi/lo split ----------------
// src fp32 [L][K][NC] -> th/tl bf16 [L][NC][K]
__global__ __launch_bounds__(256) void k_cvtw(const float* __restrict__ src, int K,
                                              int lognc, ushort* __restrict__ th,
                                              ushort* __restrict__ tl) {
  int NC = 1 << lognc;
  size_t base = (size_t)blockIdx.y * K * NC;
  int i = blockIdx.x * 256 + threadIdx.x;
  if (i >= K * NC) return;
  int k = i >> lognc, c = i & (NC - 1);
  float v = src[base + i];
  ushort hi = f2bf(v);
  th[base + (size_t)c * K + k] = hi;
  tl[base + (size_t)c * K + k] = f2bf(v - bf2f(hi));
}

// ---------------- MFMA bf16x3 GEMM + BN-stats epilogue ----------------
// Y[M x COLS] = A' @ Wt^T + bias
//   AMODE 0: A' = A0
//   AMODE 1: A' = (1+*epsp)*A0 + A1
//   AMODE 2: A' = relu(A0 * bnscale[k] + bnshift[k])  (scale/shift from sum/sq inline)
template <int AMODE, int COLS, int NT>
__global__ __launch_bounds__(NT) void k_mgemm(
    int M, int K, const float* __restrict__ A0, const float* __restrict__ A1,
    const float* __restrict__ epsp, const float* __restrict__ bnsum,
    const float* __restrict__ bnsq, const float* __restrict__ bngam,
    const float* __restrict__ bnbet, float invPrevM,
    const ushort* __restrict__ Wth, const ushort* __restrict__ Wtl,
    const float* __restrict__ bias, float* __restrict__ Y,
    float* __restrict__ colsum, float* __restrict__ colsq) {
  constexpr int NWC = COLS / 64;
  __shared__ __align__(16) ushort Ah[4][128][8];
  __shared__ __align__(16) ushort Al[4][128][8];
  __shared__ __align__(16) ushort Bh[4][COLS][8];
  __shared__ __align__(16) ushort Bl[4][COLS][8];
  __shared__ float bnsc[AMODE == 2 ? 256 : 1];
  __shared__ float bnsh[AMODE == 2 ? 256 : 1];
  const int tid = threadIdx.x;
  const int row0 = blockIdx.x * 128;
  const int lane = tid & 63, w = tid >> 6;
  const int wr = w / NWC, wc = w % NWC;
  const int kc = lane >> 4, lr = lane & 15;

  if (AMODE == 2) {
    for (int c = tid; c < K; c += NT) {
      float mu = bnsum[c] * invPrevM;
      float var = bnsq[c] * invPrevM - mu * mu;
      float sc = bngam[c] * rsqrtf(var + 1e-5f);
      bnsc[c] = sc;
      bnsh[c] = bnbet[c] - mu * sc;
    }
    __syncthreads();
  }

  float ef = 0.f;
  if (AMODE == 1) ef = 1.f + *epsp;
  f32x4 acc[4][4] = {};

  for (int k0 = 0; k0 < K; k0 += 32) {
    // ---- stage A' (fused prologue + hi/lo split) ----
    for (int i = tid; i < 512; i += NT) {
      const int c = i >> 7, r = i & 127;
      const int gk = k0 + c * 8;
      const int gr = row0 + r;
      float v[8];
      if (gr < M) {
        f32x4 a0 = *(const f32x4*)(A0 + (size_t)gr * K + gk);
        f32x4 a1 = *(const f32x4*)(A0 + (size_t)gr * K + gk + 4);
        if (AMODE == 1) {
          f32x4 g0 = *(const f32x4*)(A1 + (size_t)gr * K + gk);
          f32x4 g1 = *(const f32x4*)(A1 + (size_t)gr * K + gk + 4);
          #pragma unroll
          for (int j = 0; j < 4; ++j) {
            v[j] = fmaf(ef, a0[j], g0[j]);
            v[4 + j] = fmaf(ef, a1[j], g1[j]);
          }
        } else if (AMODE == 2) {
          f32x4 s0 = *(const f32x4*)&bnsc[gk];
          f32x4 s1 = *(const f32x4*)&bnsc[gk + 4];
          f32x4 t0 = *(const f32x4*)&bnsh[gk];
          f32x4 t1 = *(const f32x4*)&bnsh[gk + 4];
          #pragma unroll
          for (int j = 0; j < 4; ++j) {
            v[j] = fmaxf(fmaf(a0[j], s0[j], t0[j]), 0.f);
            v[4 + j] = fmaxf(fmaf(a1[j], s1[j], t1[j]), 0.f);
          }
        } else {
          #pragma unroll
          for (int j = 0; j < 4; ++j) { v[j] = a0[j]; v[4 + j] = a1[j]; }
        }
      } else {
        #pragma unroll
        for (int j = 0; j < 8; ++j) v[j] = 0.f;
      }
      alignas(16) ushort th[8], tl[8];
      #pragma unroll
      for (int j = 0; j < 8; ++j) {
        ushort hi = f2bf(v[j]);
        th[j] = hi;
        tl[j] = f2bf(v[j] - bf2f(hi));
      }
      *(uint4*)&Ah[c][r][0] = *(const uint4*)th;
      *(uint4*)&Al[c][r][0] = *(const uint4*)tl;
    }
    // ---- stage B ----
    for (int i = tid; i < COLS * 4; i += NT) {
      const int c = i / COLS, r = i % COLS;
      const int gk = k0 + c * 8;
      *(uint4*)&Bh[c][r][0] = *(const uint4*)(Wth + (size_t)r * K + gk);
      *(uint4*)&Bl[c][r][0] = *(const uint4*)(Wtl + (size_t)r * K + gk);
    }
    __syncthreads();
    // ---- MFMA: 3-term bf16 emulation of fp32 ----
    bf16x8 bhf[4], blf[4];
    #pragma unroll
    for (int fc = 0; fc < 4; ++fc) {
      bhf[fc] = *(const bf16x8*)&Bh[kc][wc * 64 + fc * 16 + lr][0];
      blf[fc] = *(const bf16x8*)&Bl[kc][wc * 64 + fc * 16 + lr][0];
    }
    #pragma unroll
    for (int fr = 0; fr < 4; ++fr) {
      bf16x8 ahf = *(const bf16x8*)&Ah[kc][wr * 64 + fr * 16 + lr][0];
      bf16x8 alf = *(const bf16x8*)&Al[kc][wr * 64 + fr * 16 + lr][0];
      #pragma unroll
      for (int fc = 0; fc < 4; ++fc) {
        acc[fr][fc] = __builtin_amdgcn_mfma_f32_16x16x32_bf16(ahf, bhf[fc], acc[fr][fc], 0, 0, 0);
        acc[fr][fc] = __builtin_amdgcn_mfma_f32_16x16x32_bf16(alf, bhf[fc], acc[fr][fc], 0, 0, 0);
        acc[fr][fc] = __builtin_amdgcn_mfma_f32_16x16x32_bf16(ahf, blf[fc], acc[fr][fc], 0, 0, 0);
      }
    }
    __syncthreads();
  }

  // ---- epilogue: bias, store, per-column stats ----
  #pragma unroll
  for (int fc = 0; fc < 4; ++fc) {
    const int gc = wc * 64 + fc * 16 + lr;
    const float bb = bias[gc];
    float cs = 0.f, cq = 0.f;
    #pragma unroll
    for (int fr = 0; fr < 4; ++fr) {
      const int rb = row0 + wr * 64 + fr * 16 + kc * 4;
      #pragma unroll
      for (int rg = 0; rg < 4; ++rg) {
        int gr = rb + rg;
        if (gr < M) {
          float v = acc[fr][fc][rg] + bb;
          Y[(size_t)gr * COLS + gc] = v;
          cs += v;
          cq += v * v;
        }
      }
    }
    cs += __shfl_xor(cs, 16); cs += __shfl_xor(cs, 32);
    cq += __shfl_xor(cq, 16); cq += __shfl_xor(cq, 32);
    if (kc == 0) {
      atomicAdd(&colsum[gc], cs);
      atomicAdd(&colsq[gc], cq);
    }
  }
}

// ---------------- graph pooling ----------------

DEV void k_pool(const float* __restrict__ hv, const int* __restrict__ batch,
                const float* __restrict__ vn, float* __restrict__ vt) {
  int g = blockIdx.x;
  int lo = 0, hi = NN;
  while (lo < hi) { int mid = (lo + hi) >> 1; if (batch[mid] < g) lo = mid + 1; else hi = mid; }
  int s = lo;
  hi = NN;
  while (lo < hi) { int mid = (lo + hi) >> 1; if (batch[mid] < g + 1) lo = mid + 1; else hi = mid; }
  int e = lo;
  int ry = threadIdx.x >> 5, cx = threadIdx.x & 31;
  float4 acc = make_float4(0.f, 0.f, 0.f, 0.f);
  for (int n = s + ry; n < e; n += 8) {
    float4 v = *(const float4*)(hv + (size_t)n * D + cx * 4);
    acc.x += v.x; acc.y += v.y; acc.z += v.z; acc.w += v.w;
  }
  __shared__ float4 red[8][32];
  red[ry][cx] = acc;
  __syncthreads();
  for (int st = 4; st >= 1; st >>= 1) {
    if (ry < st) {
      float4 o = red[ry + st][cx];
      red[ry][cx].x += o.x; red[ry][cx].y += o.y;
      red[ry][cx].z += o.z; red[ry][cx].w += o.w;
    }
    __syncthreads();
  }
  if (ry == 0) {
    float4 v = red[0][cx];
    float4 b = *(const float4*)(vn + (size_t)g * D + cx * 4);
    v.x += b.x; v.y += b.y; v.z += b.z; v.w += b.w;
    *(float4*)(vt + (size_t)g * D + cx * 4) = v;
  }
}

// ---------------- launcher ----------------

extern "C" void kernel_launch(void* const* d_in, const int* in_sizes, int n_in,
                              void* d_out, int out_size, void* d_ws, size_t ws_size,
                              hipStream_t stream) {
  const int* x = (const int*)d_in[0];
  const int* ei = (const int*)d_in[1];
  const int* eattr = (const int*)d_in[2];
  const int* batch = (const int*)d_in[3];
  const float* atom_emb = (const float*)d_in[4];
  const float* bond_emb = (const float*)d_in[5];
  const float* eps = (const float*)d_in[6];
  const float* conv_w1 = (const float*)d_in[7];
  const float* conv_b1 = (const float*)d_in[8];
  const float* conv_bn_g = (const float*)d_in[9];
  const float* conv_bn_b = (const float*)d_in[10];
  const float* conv_w2 = (const float*)d_in[11];
  const float* conv_b2 = (const float*)d_in[12];
  const float* bn_g = (const float*)d_in[13];
  const float* bn_b = (const float*)d_in[14];
  const float* vn_emb = (const float*)d_in[15];
  const float* vn_w1 = (const float*)d_in[16];
  const float* vn_b1 = (const float*)d_in[17];
  const float* vn_bn1_g = (const float*)d_in[18];
  const float* vn_bn1_b = (const float*)d_in[19];
  const float* vn_w2 = (const float*)d_in[20];
  const float* vn_b2 = (const float*)d_in[21];
  const float* vn_bn2_g = (const float*)d_in[22];
  const float* vn_bn2_b = (const float*)d_in[23];
  float* out = (float*)d_out;

  char* w = (char*)d_ws;
  auto alloc = [&](size_t bytes) {
    char* p = w;
    w += (bytes + 255) & ~((size_t)255);
    return p;
  };
  float* h   = (float*)alloc((size_t)NN * D * 4);     // z buffer (mgemm2 out)
  float* hv  = (float*)alloc((size_t)NN * D * 4);
  float* agg = (float*)alloc((size_t)NN * D * 4);
  float* y   = (float*)alloc((size_t)NN * 256 * 4);
  float* vn  = (float*)alloc((size_t)NG * D * 4);
  float* vt  = (float*)alloc((size_t)NG * D * 4);
  float* yv  = (float*)alloc((size_t)NG * 256 * 4);
  float* zv  = (float*)alloc((size_t)NG * D * 4);
  float* stats = (float*)alloc(16 * 512 * 4);  // 10 slots of (sum[256],sq[256])
  auto SUM = [&](int slot) { return stats + slot * 512; };
  auto SQ  = [&](int slot) { return stats + slot * 512 + 256; };
  int* cnt = (int*)alloc((size_t)NN * 4);
  int* rowptr = (int*)alloc((size_t)(NN + 1) * 4);
  int* cursor = (int*)alloc((size_t)NN * 4);
  unsigned* csr = (unsigned*)alloc((size_t)NE * 4);
  int* bsum = (int*)alloc(128 * 4);
  ushort* wt1h = (ushort*)alloc((size_t)NL * 256 * 128 * 2);
  ushort* wt1l = (ushort*)alloc((size_t)NL * 256 * 128 * 2);
  ushort* wt2h = (ushort*)alloc((size_t)NL * 128 * 256 * 2);
  ushort* wt2l = (ushort*)alloc((size_t)NL * 128 * 256 * 2);
  ushort* vw1h = (ushort*)alloc((size_t)2 * 256 * 128 * 2);
  ushort* vw1l = (ushort*)alloc((size_t)2 * 256 * 128 * 2);
  ushort* vw2h = (ushort*)alloc((size_t)2 * 128 * 256 * 2);
  ushort* vw2l = (ushort*)alloc((size_t)2 * 128 * 256 * 2);

  // one memset for all BN stat slots
  hipMemsetAsync(stats, 0, 16 * 512 * 4, stream);

  // weight transpose + split
  k_cvtw<<<dim3(128, NL), 256, 0, stream>>>(conv_w1, 128, 8, wt1h, wt1l);
  k_cvtw<<<dim3(128, NL), 256, 0, stream>>>(conv_w2, 256, 7, wt2h, wt2l);
  k_cvtw<<<dim3(128, 2), 256, 0, stream>>>(vn_w1, 128, 8, vw1h, vw1l);
  k_cvtw<<<dim3(128, 2), 256, 0, stream>>>(vn_w2, 256, 7, vw2h, vw2l);

  // encoders (vn broadcast fused into atom encoder) + vn buffer init
  k_atom<<<(NN * 32 + 255) / 256, 256, 0, stream>>>(x, atom_emb, vn_emb, hv);
  k_vninit<<<(NG * 32 + 255) / 256, 256, 0, stream>>>(vn_emb, vn);

  // CSR build (reused by all 3 layers)
  hipMemsetAsync(cnt, 0, (size_t)NN * 4, stream);
  k_hist<<<(NE + 255) / 256, 256, 0, stream>>>(ei, cnt);
  k_scan_a<<<NBLK, SCAN_B, 0, stream>>>(cnt, rowptr, bsum);
  k_scan_b<<<1, 64, 0, stream>>>(bsum, NBLK);
  k_scan_c<<<NBLK, SCAN_B, 0, stream>>>(rowptr, bsum);
  hipMemcpyAsync(cursor, rowptr, (size_t)NN * 4, hipMemcpyDeviceToDevice, stream);
  k_fill<<<(NE + 255) / 256, 256, 0, stream>>>(ei, eattr, cursor, csr);

  const int gx = (NN + 127) / 128;  // 391
  const int gv = (NG + 127) / 128;  // 4
  for (int l = 0; l < NL; ++l) {
    const int sc1 = l, sc2 = 3 + l, sv1 = 6 + l, sv2 = 8 + l;
    k_agg<<<(NN * 64 + 255) / 256, 256, 0, stream>>>(
        hv, csr, rowptr, bond_emb + (size_t)l * 3 * 8 * D, agg);

    k_mgemm<1, 256, 512><<<gx, 512, 0, stream>>>(
        NN, 128, hv, agg, eps + l, nullptr, nullptr, nullptr, nullptr, 0.f,
        wt1h + (size_t)l * 256 * 128, wt1l + (size_t)l * 256 * 128,
        conv_b1 + l * 256, y, SUM(sc1), SQ(sc1));
    k_mgemm<2, 128, 256><<<gx, 256, 0, stream>>>(
        NN, 256, y, nullptr, nullptr, SUM(sc1), SQ(sc1),
        conv_bn_g + l * 256, conv_bn_b + l * 256, 1.f / NN,
        wt2h + (size_t)l * 128 * 256, wt2l + (size_t)l * 128 * 256,
        conv_b2 + l * 128, h, SUM(sc2), SQ(sc2));

    if (l < NL - 1) {
      k_pool<<<NG, 256, 0, stream>>>(hv, batch, vn, vt);
      k_mgemm<0, 256, 512><<<gv, 512, 0, stream>>>(
          NG, 128, vt, nullptr, nullptr, nullptr, nullptr, nullptr, nullptr, 0.f,
          vw1h + (size_t)l * 256 * 128, vw1l + (size_t)l * 256 * 128,
          vn_b1 + l * 256, yv, SUM(sv1), SQ(sv1));
      k_mgemm<2, 128, 256><<<gv, 256, 0, stream>>>(
          NG, 256, yv, nullptr, nullptr, SUM(sv1), SQ(sv1),
          vn_bn1_g + l * 256, vn_bn1_b + l * 256, 1.f / NG,
          vw2h + (size_t)l * 128 * 256, vw2l + (size_t)l * 128 * 256,
          vn_b2 + l * 128, zv, SUM(sv2), SQ(sv2));
      // vn = relu(bn2(zv))
      k_post<<<(NG * 32 + 255) / 256, 256, 0, stream>>>(
          zv, SUM(sv2), SQ(sv2), vn_bn2_g + l * 128, vn_bn2_b + l * 128,
          1.f / NG, nullptr, nullptr, vn, NG, 1);
      // hv_next = relu(bn(z)) + vn_new[batch]
      k_post<<<(NN * 32 + 255) / 256, 256, 0, stream>>>(
          h, SUM(sc2), SQ(sc2), bn_g + l * 128, bn_b + l * 128,
          1.f / NN, vn, batch, hv, NN, 1);
    } else {
      // final output: bn(z), no relu
      k_post<<<(NN * 32 + 255) / 256, 256, 0, stream>>>(
          h, SUM(sc2), SQ(sc2), bn_g + l * 128, bn_b + l * 128,
          1.f / NN, nullptr, nullptr, out, NN, 0);
    }
  }
}